// Round 6
// baseline (129.784 us; speedup 1.0000x reference)
//
#include <hip/hip_runtime.h>
#include <hip/hip_bf16.h>

// Problem constants (match reference)
constexpr int kB = 64, kN = 600, kR = 40, kL = 50;
constexpr int kMinLen = 2, kMaxLen = 48;
constexpr int kNN  = kN * kN;      // 360000 elements per batch
constexpr int kNN4 = kNN / 4;      // 90000 float4 per batch

// Launch geometry: per-batch contiguous chunks, oversubscribed grid.
// 7552 blocks vs ~2048 resident -> ~3.7 generations, so per-CU load
// imbalance rebalances per chunk instead of per kernel (round-5: one-shot
// cohort gave 58% occupancy / long drain tail).
constexpr int kBlk   = 256;
constexpr int kChunk = 768;                          // float4 per block (3 steps)
constexpr int kGX    = (kNN4 + kChunk - 1) / kChunk; // 118 blocks per batch
constexpr int kSteps = kChunk / kBlk;                // 3

// native clang vector type for nontemporal stores
typedef float f32x4 __attribute__((ext_vector_type(4)));

// Output layout (flat f32, concatenated in reference return order)
constexpr int OFF_TDT = 0;                  // total_demand_time   [B]
constexpr int OFF_TRT = kB;                 // total_route_time    [B]   (passthrough)
constexpr int OFF_TAT = 2 * kB;             // trips_at_transfers  [B,4]
constexpr int OFF_TD  = OFF_TAT + 4 * kB;   // total_demand        [B]
constexpr int OFF_UD  = OFF_TD + kB;        // unserved_demand     [B]
constexpr int OFF_TTR = OFF_UD + kB;        // total_transfers     [B]
constexpr int OFF_TT  = OFF_TTR + kB;       // trip_times          [B,N,N]
constexpr int OFF_OOB = OFF_TT + kB * kNN;  // n_stops_oob         [B]
constexpr int OFF_NSV = OFF_OOB + kB;       // n_stops_visited     [B,R]

__device__ __forceinline__ void proc4(const float4& d, const float4& t,
                                      const int4& nt, const int4& hp,
                                      f32x4& tt, float acc[8]) {
#define PROC(C, IDX)                                     \
    {                                                    \
        const bool  h  = (hp.C != 0);                    \
        const float dv = d.C;                            \
        const int   n  = nt.C;                           \
        const float tv = h ? t.C : 0.0f;                 \
        tt[IDX] = tv;                                    \
        acc[0] = fmaf(dv, tv, acc[0]);                   \
        const int ne = h ? n : 3;                        \
        acc[1] += (ne == 0) ? dv : 0.0f;                 \
        acc[2] += (ne == 1) ? dv : 0.0f;                 \
        acc[3] += (ne == 2) ? dv : 0.0f;                 \
        acc[4] += (ne >  2) ? dv : 0.0f;                 \
        acc[5] += dv;                                    \
        acc[6] += h ? 0.0f : dv;                         \
        acc[7] = fmaf(dv, (float)n, acc[7]);             \
    }
    PROC(x, 0) PROC(y, 1) PROC(z, 2) PROC(w, 3)
#undef PROC
}

// Fused elementwise + per-batch reductions over [B, N*N].
// grid = (kGX, B), block = 256. Per-batch slots must be pre-zeroed.
// No min-waves bound: round 3 showed forcing 8 waves/EU spills (WRITE 2.2x).
__global__ __launch_bounds__(kBlk) void fused_main(
    const float* __restrict__ demand,
    const float* __restrict__ transit,
    const int* __restrict__ ntrans,
    const int* __restrict__ haspath,   // jax bool widened to i32 on device
    float* __restrict__ out)
{
    const int b = blockIdx.y;
    const int base = b * kNN;
    const float4* __restrict__ d4 = (const float4*)(demand + base);
    const float4* __restrict__ t4 = (const float4*)(transit + base);
    const int4*   __restrict__ n4 = (const int4*)(ntrans + base);
    const int4*   __restrict__ h4 = (const int4*)(haspath + base);
    f32x4* __restrict__ o4 = (f32x4*)(out + OFF_TT + base);

    // contiguous per-block chunk: sequential 12 KB/array stream
    const int i0 = blockIdx.x * kChunk + threadIdx.x;
    float acc[8] = {0.f, 0.f, 0.f, 0.f, 0.f, 0.f, 0.f, 0.f};

#pragma unroll
    for (int k = 0; k < kSteps; ++k) {
        const int i = i0 + k * kBlk;
        if (i < kNN4) {
            const float4 d  = d4[i];
            const float4 t  = t4[i];
            const int4   nt = n4[i];
            const int4   hp = h4[i];
            f32x4 tt;
            proc4(d, t, nt, hp, tt, acc);
            // write-once streamed output: keep out of L2/L3 so caches serve
            // the 369 MB read set instead
            __builtin_nontemporal_store(tt, &o4[i]);
        }
    }

    // wave(64) shuffle reduce, then cross-wave via LDS, then 8 atomics/block
#pragma unroll
    for (int j = 0; j < 8; ++j) {
        float v = acc[j];
#pragma unroll
        for (int off = 32; off > 0; off >>= 1) v += __shfl_down(v, off, 64);
        acc[j] = v;
    }
    __shared__ float lds[4][8];
    const int lane = threadIdx.x & 63;
    const int wid  = threadIdx.x >> 6;
    if (lane == 0) {
#pragma unroll
        for (int j = 0; j < 8; ++j) lds[wid][j] = acc[j];
    }
    __syncthreads();
    if (threadIdx.x < 8) {
        const int j = threadIdx.x;
        const float v = lds[0][j] + lds[1][j] + lds[2][j] + lds[3][j];
        int idx;
        if (j == 0)      idx = OFF_TDT + b;
        else if (j <= 4) idx = OFF_TAT + b * 4 + (j - 1);
        else if (j == 5) idx = OFF_TD + b;
        else if (j == 6) idx = OFF_UD + b;
        else             idx = OFF_TTR + b;
        atomicAdd(&out[idx], v);
    }
}

// One wave per (b, r) route row: length, distinct-stop count, OOB penalty.
__global__ __launch_bounds__(256) void routes_kernel(
    const int* __restrict__ routes,
    const int* __restrict__ nleft,
    const int* __restrict__ hascur,    // bool widened to i32
    float* __restrict__ out)
{
    const int row  = (blockIdx.x * blockDim.x + threadIdx.x) >> 6; // (b*R + r)
    const int lane = threadIdx.x & 63;
    if (row >= kB * kR) return;
    const int b = row / kR;
    const int r = row % kR;

    const int v = (lane < kL) ? routes[row * kL + lane] : -1;
    const bool valid = (v > -1);
    bool dup = false;
#pragma unroll
    for (int k = 0; k < kL; ++k) {
        const int vk = __shfl(v, k, 64);
        if (k < lane && vk == v) dup = true;
    }
    const int len  = __popcll(__ballot(valid));
    const int dist = __popcll(__ballot(valid && !dup));

    if (lane == 0) {
        int delta = (kMinLen - len > 0) ? (kMinLen - len) : 0;
        if (len == 0) delta = 0;
        delta += (len - kMaxLen > 0) ? (len - kMaxLen) : 0;
        float add = (float)delta;
        if (r == 0) {
            const float nun = (float)nleft[b] - (hascur[b] ? 1.0f : 0.0f);
            add += nun * (float)kMinLen;
        }
        atomicAdd(&out[OFF_OOB + b], add);
        out[OFF_NSV + row] = (float)dist;
    }
}

extern "C" void kernel_launch(void* const* d_in, const int* in_sizes, int n_in,
                              void* d_out, int out_size, void* d_ws, size_t ws_size,
                              hipStream_t stream) {
    const float* demand  = (const float*)d_in[0];
    const float* transit = (const float*)d_in[1];
    const float* trt     = (const float*)d_in[2];
    const int*   routes  = (const int*)d_in[3];
    const int*   ntrans  = (const int*)d_in[4];
    const int*   haspath = (const int*)d_in[5];
    const int*   nleft   = (const int*)d_in[6];
    const int*   hascur  = (const int*)d_in[7];
    // d_in[8] (n_disconnected_demand_edges) is unused by the reference.
    float* out = (float*)d_out;

    // zero accumulation slots (graph-capturable async ops, ordered on stream)
    (void)hipMemsetAsync(out, 0, OFF_TT * sizeof(float), stream);
    (void)hipMemsetAsync(out + OFF_OOB, 0, kB * sizeof(float), stream);
    // total_route_time passthrough
    (void)hipMemcpyAsync(out + OFF_TRT, trt, kB * sizeof(float),
                         hipMemcpyDeviceToDevice, stream);

    fused_main<<<dim3(kGX, kB), kBlk, 0, stream>>>(demand, transit, ntrans, haspath, out);

    const int nrows = kB * kR;                 // 2560 waves, one per route row
    const int nthreads = nrows * 64;
    routes_kernel<<<(nthreads + 255) / 256, 256, 0, stream>>>(routes, nleft, hascur, out);
}

// Round 7
// 120.968 us; speedup vs baseline: 1.0729x; 1.0729x over previous
//
#include <hip/hip_runtime.h>
#include <hip/hip_bf16.h>

// Problem constants (match reference)
constexpr int kB = 64, kN = 600, kR = 40, kL = 50;
constexpr int kMinLen = 2, kMaxLen = 48;
constexpr int kNN  = kN * kN;      // 360000 elements per batch
constexpr int kNN4 = kNN / 4;      // 90000 float4 per batch

// Geometry: 32 blocks/batch (2048 total), 128 waves/batch.
// Each wave owns adjacent pairs: [wavebase, +64) and [wavebase+64, +128)
// -> 2 KB contiguous per array per step (DRAM-row friendly), and the
// k+1 prefetch keeps 8 loads in flight during compute.
constexpr int kBlk     = 256;
constexpr int kGX      = 32;
constexpr int kWavesPB = kGX * kBlk / 64;   // 128 waves per batch
constexpr int kStride  = kWavesPB * 128;    // 16384 float4 per pipeline step
constexpr int kIters   = kNN4 / kStride;    // 5 full steps (81920)
// tail [81920, 90000) handled with guards

// native clang vector type for nontemporal stores
typedef float f32x4 __attribute__((ext_vector_type(4)));

// Output layout (flat f32, concatenated in reference return order)
constexpr int OFF_TDT = 0;                  // total_demand_time   [B]
constexpr int OFF_TRT = kB;                 // total_route_time    [B]   (passthrough)
constexpr int OFF_TAT = 2 * kB;             // trips_at_transfers  [B,4]
constexpr int OFF_TD  = OFF_TAT + 4 * kB;   // total_demand        [B]
constexpr int OFF_UD  = OFF_TD + kB;        // unserved_demand     [B]
constexpr int OFF_TTR = OFF_UD + kB;        // total_transfers     [B]
constexpr int OFF_TT  = OFF_TTR + kB;       // trip_times          [B,N,N]
constexpr int OFF_OOB = OFF_TT + kB * kNN;  // n_stops_oob         [B]
constexpr int OFF_NSV = OFF_OOB + kB;       // n_stops_visited     [B,R]

__device__ __forceinline__ void proc4(const float4& d, const float4& t,
                                      const int4& nt, const int4& hp,
                                      f32x4& tt, float acc[8]) {
#define PROC(C, IDX)                                     \
    {                                                    \
        const bool  h  = (hp.C != 0);                    \
        const float dv = d.C;                            \
        const int   n  = nt.C;                           \
        const float tv = h ? t.C : 0.0f;                 \
        tt[IDX] = tv;                                    \
        acc[0] = fmaf(dv, tv, acc[0]);                   \
        const int ne = h ? n : 3;                        \
        acc[1] += (ne == 0) ? dv : 0.0f;                 \
        acc[2] += (ne == 1) ? dv : 0.0f;                 \
        acc[3] += (ne == 2) ? dv : 0.0f;                 \
        acc[4] += (ne >  2) ? dv : 0.0f;                 \
        acc[5] += dv;                                    \
        acc[6] += h ? 0.0f : dv;                         \
        acc[7] = fmaf(dv, (float)n, acc[7]);             \
    }
    PROC(x, 0) PROC(y, 1) PROC(z, 2) PROC(w, 3)
#undef PROC
}

// Fused elementwise + per-batch reductions over [B, N*N].
// grid = (kGX, B), block = 256. Per-batch slots must be pre-zeroed.
// No min-waves bound (round 3: forcing 8 waves/EU spilled, WRITE 2.2x).
// Register double-buffered pipeline: prefetch k+1's 8 loads before
// computing k (round 5's VGPR=40 showed the compiler had re-serialized
// the "clustered" loads; this structure forces two iterations live).
__global__ __launch_bounds__(kBlk) void fused_main(
    const float* __restrict__ demand,
    const float* __restrict__ transit,
    const int* __restrict__ ntrans,
    const int* __restrict__ haspath,   // jax bool widened to i32 on device
    float* __restrict__ out)
{
    const int b = blockIdx.y;
    const int base = b * kNN;
    const float4* __restrict__ d4 = (const float4*)(demand + base);
    const float4* __restrict__ t4 = (const float4*)(transit + base);
    const int4*   __restrict__ n4 = (const int4*)(ntrans + base);
    const int4*   __restrict__ h4 = (const int4*)(haspath + base);
    f32x4* __restrict__ o4 = (f32x4*)(out + OFF_TT + base);

    const int tid  = blockIdx.x * kBlk + threadIdx.x;
    const int w    = tid >> 6;
    const int lane = tid & 63;

    float acc[8] = {0.f, 0.f, 0.f, 0.f, 0.f, 0.f, 0.f, 0.f};

    // ---- software pipeline over 5 full steps ----
    int ia = w * 128 + lane;
    int ib = ia + 64;
    float4 dA = d4[ia], dB = d4[ib];
    float4 tA = t4[ia], tB = t4[ib];
    int4   nA = n4[ia], nB = n4[ib];
    int4   hA = h4[ia], hB = h4[ib];

#pragma unroll
    for (int k = 0; k < kIters; ++k) {
        const int ja = ia + kStride, jb = ib + kStride;
        float4 dA2, dB2, tA2, tB2;
        int4   nA2, nB2, hA2, hB2;
        if (k + 1 < kIters) {           // compile-time resolved
            dA2 = d4[ja]; dB2 = d4[jb];
            tA2 = t4[ja]; tB2 = t4[jb];
            nA2 = n4[ja]; nB2 = n4[jb];
            hA2 = h4[ja]; hB2 = h4[jb];
        }
        f32x4 oA, oB;
        proc4(dA, tA, nA, hA, oA, acc);
        proc4(dB, tB, nB, hB, oB, acc);
        __builtin_nontemporal_store(oA, &o4[ia]);
        __builtin_nontemporal_store(oB, &o4[ib]);
        if (k + 1 < kIters) {
            dA = dA2; dB = dB2; tA = tA2; tB = tB2;
            nA = nA2; nB = nB2; hA = hA2; hB = hB2;
            ia = ja; ib = jb;
        }
    }

    // ---- tail [81920, 90000) ----
    {
        const int ta = kIters * kStride + w * 128 + lane;
        const int tb = ta + 64;
        if (ta < kNN4) {
            const float4 d  = d4[ta];
            const float4 t  = t4[ta];
            const int4   nt = n4[ta];
            const int4   hp = h4[ta];
            f32x4 tt;
            proc4(d, t, nt, hp, tt, acc);
            __builtin_nontemporal_store(tt, &o4[ta]);
        }
        if (tb < kNN4) {
            const float4 d  = d4[tb];
            const float4 t  = t4[tb];
            const int4   nt = n4[tb];
            const int4   hp = h4[tb];
            f32x4 tt;
            proc4(d, t, nt, hp, tt, acc);
            __builtin_nontemporal_store(tt, &o4[tb]);
        }
    }

    // wave(64) shuffle reduce, then cross-wave via LDS, then 8 atomics/block
#pragma unroll
    for (int j = 0; j < 8; ++j) {
        float v = acc[j];
#pragma unroll
        for (int off = 32; off > 0; off >>= 1) v += __shfl_down(v, off, 64);
        acc[j] = v;
    }
    __shared__ float lds[4][8];
    const int llane = threadIdx.x & 63;
    const int wid   = threadIdx.x >> 6;
    if (llane == 0) {
#pragma unroll
        for (int j = 0; j < 8; ++j) lds[wid][j] = acc[j];
    }
    __syncthreads();
    if (threadIdx.x < 8) {
        const int j = threadIdx.x;
        const float v = lds[0][j] + lds[1][j] + lds[2][j] + lds[3][j];
        int idx;
        if (j == 0)      idx = OFF_TDT + b;
        else if (j <= 4) idx = OFF_TAT + b * 4 + (j - 1);
        else if (j == 5) idx = OFF_TD + b;
        else if (j == 6) idx = OFF_UD + b;
        else             idx = OFF_TTR + b;
        atomicAdd(&out[idx], v);
    }
}

// One wave per (b, r) route row: length, distinct-stop count, OOB penalty.
__global__ __launch_bounds__(256) void routes_kernel(
    const int* __restrict__ routes,
    const int* __restrict__ nleft,
    const int* __restrict__ hascur,    // bool widened to i32
    float* __restrict__ out)
{
    const int row  = (blockIdx.x * blockDim.x + threadIdx.x) >> 6; // (b*R + r)
    const int lane = threadIdx.x & 63;
    if (row >= kB * kR) return;
    const int b = row / kR;
    const int r = row % kR;

    const int v = (lane < kL) ? routes[row * kL + lane] : -1;
    const bool valid = (v > -1);
    bool dup = false;
#pragma unroll
    for (int k = 0; k < kL; ++k) {
        const int vk = __shfl(v, k, 64);
        if (k < lane && vk == v) dup = true;
    }
    const int len  = __popcll(__ballot(valid));
    const int dist = __popcll(__ballot(valid && !dup));

    if (lane == 0) {
        int delta = (kMinLen - len > 0) ? (kMinLen - len) : 0;
        if (len == 0) delta = 0;
        delta += (len - kMaxLen > 0) ? (len - kMaxLen) : 0;
        float add = (float)delta;
        if (r == 0) {
            const float nun = (float)nleft[b] - (hascur[b] ? 1.0f : 0.0f);
            add += nun * (float)kMinLen;
        }
        atomicAdd(&out[OFF_OOB + b], add);
        out[OFF_NSV + row] = (float)dist;
    }
}

extern "C" void kernel_launch(void* const* d_in, const int* in_sizes, int n_in,
                              void* d_out, int out_size, void* d_ws, size_t ws_size,
                              hipStream_t stream) {
    const float* demand  = (const float*)d_in[0];
    const float* transit = (const float*)d_in[1];
    const float* trt     = (const float*)d_in[2];
    const int*   routes  = (const int*)d_in[3];
    const int*   ntrans  = (const int*)d_in[4];
    const int*   haspath = (const int*)d_in[5];
    const int*   nleft   = (const int*)d_in[6];
    const int*   hascur  = (const int*)d_in[7];
    // d_in[8] (n_disconnected_demand_edges) is unused by the reference.
    float* out = (float*)d_out;

    // zero accumulation slots (graph-capturable async ops, ordered on stream)
    (void)hipMemsetAsync(out, 0, OFF_TT * sizeof(float), stream);
    (void)hipMemsetAsync(out + OFF_OOB, 0, kB * sizeof(float), stream);
    // total_route_time passthrough
    (void)hipMemcpyAsync(out + OFF_TRT, trt, kB * sizeof(float),
                         hipMemcpyDeviceToDevice, stream);

    fused_main<<<dim3(kGX, kB), kBlk, 0, stream>>>(demand, transit, ntrans, haspath, out);

    const int nrows = kB * kR;                 // 2560 waves, one per route row
    const int nthreads = nrows * 64;
    routes_kernel<<<(nthreads + 255) / 256, 256, 0, stream>>>(routes, nleft, hascur, out);
}

// Round 8
// 119.461 us; speedup vs baseline: 1.0864x; 1.0126x over previous
//
#include <hip/hip_runtime.h>
#include <hip/hip_bf16.h>

// Problem constants (match reference)
constexpr int kB = 64, kN = 600, kR = 40, kL = 50;
constexpr int kMinLen = 2, kMaxLen = 48;
constexpr int kNN  = kN * kN;      // 360000 elements per batch
constexpr int kNN4 = kNN / 4;      // 90000 float4 per batch

// Geometry: contiguous 1024-float4 chunk per block, 88 blocks/batch
// -> 5632 blocks (~2.75 resident generations: tail rebalances, r6 lesson)
// combined with r5's paired 2-deep load cluster (8 loads in flight, r7 lesson).
constexpr int kBlk   = 256;
constexpr int kChunk = 1024;
constexpr int kGX    = (kNN4 + kChunk - 1) / kChunk;  // 88
// chunk sub-positions: p = i0 + {0,256,512,768}; only p3 can exceed kNN4
// (last block: 89856..90111 vs kNN4=90000) -> single guard on p3.

// native clang vector type for nontemporal stores
typedef float f32x4 __attribute__((ext_vector_type(4)));

// Output layout (flat f32, concatenated in reference return order)
constexpr int OFF_TDT = 0;                  // total_demand_time   [B]
constexpr int OFF_TRT = kB;                 // total_route_time    [B]   (passthrough)
constexpr int OFF_TAT = 2 * kB;             // trips_at_transfers  [B,4]
constexpr int OFF_TD  = OFF_TAT + 4 * kB;   // total_demand        [B]
constexpr int OFF_UD  = OFF_TD + kB;        // unserved_demand     [B]
constexpr int OFF_TTR = OFF_UD + kB;        // total_transfers     [B]
constexpr int OFF_TT  = OFF_TTR + kB;       // trip_times          [B,N,N]
constexpr int OFF_OOB = OFF_TT + kB * kNN;  // n_stops_oob         [B]
constexpr int OFF_NSV = OFF_OOB + kB;       // n_stops_visited     [B,R]

__device__ __forceinline__ void proc4(const float4& d, const float4& t,
                                      const int4& nt, const int4& hp,
                                      f32x4& tt, float acc[8]) {
#define PROC(C, IDX)                                     \
    {                                                    \
        const bool  h  = (hp.C != 0);                    \
        const float dv = d.C;                            \
        const int   n  = nt.C;                           \
        const float tv = h ? t.C : 0.0f;                 \
        tt[IDX] = tv;                                    \
        acc[0] = fmaf(dv, tv, acc[0]);                   \
        const int ne = h ? n : 3;                        \
        acc[1] += (ne == 0) ? dv : 0.0f;                 \
        acc[2] += (ne == 1) ? dv : 0.0f;                 \
        acc[3] += (ne == 2) ? dv : 0.0f;                 \
        acc[4] += (ne >  2) ? dv : 0.0f;                 \
        acc[5] += dv;                                    \
        acc[6] += h ? 0.0f : dv;                         \
        acc[7] = fmaf(dv, (float)n, acc[7]);             \
    }
    PROC(x, 0) PROC(y, 1) PROC(z, 2) PROC(w, 3)
#undef PROC
}

// Fused elementwise + per-batch reductions over [B, N*N].
// grid = (kGX, B), block = 256. Per-batch slots must be pre-zeroed.
// No min-waves bound (round 3: forcing 8 waves/EU spilled, WRITE 2.2x).
__global__ __launch_bounds__(kBlk) void fused_main(
    const float* __restrict__ demand,
    const float* __restrict__ transit,
    const int* __restrict__ ntrans,
    const int* __restrict__ haspath,   // jax bool widened to i32 on device
    float* __restrict__ out)
{
    const int b = blockIdx.y;
    const int base = b * kNN;
    const float4* __restrict__ d4 = (const float4*)(demand + base);
    const float4* __restrict__ t4 = (const float4*)(transit + base);
    const int4*   __restrict__ n4 = (const int4*)(ntrans + base);
    const int4*   __restrict__ h4 = (const int4*)(haspath + base);
    f32x4* __restrict__ o4 = (f32x4*)(out + OFF_TT + base);

    const int i0 = blockIdx.x * kChunk + threadIdx.x;
    const int p0 = i0, p1 = i0 + kBlk, p2 = i0 + 2 * kBlk, p3 = i0 + 3 * kBlk;
    const bool v3 = (p3 < kNN4);       // only p3 can be OOB (last block)

    float acc[8] = {0.f, 0.f, 0.f, 0.f, 0.f, 0.f, 0.f, 0.f};

    // ---- pair 0: p0,p1 — 8 loads clustered ----
    {
        const float4 dA = d4[p0]; const float4 dB = d4[p1];
        const float4 tA = t4[p0]; const float4 tB = t4[p1];
        const int4   nA = n4[p0]; const int4   nB = n4[p1];
        const int4   hA = h4[p0]; const int4   hB = h4[p1];
        f32x4 oA, oB;
        proc4(dA, tA, nA, hA, oA, acc);
        proc4(dB, tB, nB, hB, oB, acc);
        __builtin_nontemporal_store(oA, &o4[p0]);
        __builtin_nontemporal_store(oB, &o4[p1]);
    }
    // ---- pair 1: p2,p3 — 8 loads clustered (p3 guarded) ----
    {
        const float4 dA = d4[p2];
        const float4 tA = t4[p2];
        const int4   nA = n4[p2];
        const int4   hA = h4[p2];
        float4 dB, tB; int4 nB, hB;
        if (v3) { dB = d4[p3]; tB = t4[p3]; nB = n4[p3]; hB = h4[p3]; }
        f32x4 oA, oB;
        proc4(dA, tA, nA, hA, oA, acc);
        __builtin_nontemporal_store(oA, &o4[p2]);
        if (v3) {
            proc4(dB, tB, nB, hB, oB, acc);
            __builtin_nontemporal_store(oB, &o4[p3]);
        }
    }

    // wave(64) shuffle reduce, then cross-wave via LDS, then 8 atomics/block
#pragma unroll
    for (int j = 0; j < 8; ++j) {
        float v = acc[j];
#pragma unroll
        for (int off = 32; off > 0; off >>= 1) v += __shfl_down(v, off, 64);
        acc[j] = v;
    }
    __shared__ float lds[4][8];
    const int lane = threadIdx.x & 63;
    const int wid  = threadIdx.x >> 6;
    if (lane == 0) {
#pragma unroll
        for (int j = 0; j < 8; ++j) lds[wid][j] = acc[j];
    }
    __syncthreads();
    if (threadIdx.x < 8) {
        const int j = threadIdx.x;
        const float v = lds[0][j] + lds[1][j] + lds[2][j] + lds[3][j];
        int idx;
        if (j == 0)      idx = OFF_TDT + b;
        else if (j <= 4) idx = OFF_TAT + b * 4 + (j - 1);
        else if (j == 5) idx = OFF_TD + b;
        else if (j == 6) idx = OFF_UD + b;
        else             idx = OFF_TTR + b;
        atomicAdd(&out[idx], v);
    }
}

// One wave per (b, r) route row: length, distinct-stop count, OOB penalty.
__global__ __launch_bounds__(256) void routes_kernel(
    const int* __restrict__ routes,
    const int* __restrict__ nleft,
    const int* __restrict__ hascur,    // bool widened to i32
    float* __restrict__ out)
{
    const int row  = (blockIdx.x * blockDim.x + threadIdx.x) >> 6; // (b*R + r)
    const int lane = threadIdx.x & 63;
    if (row >= kB * kR) return;
    const int b = row / kR;
    const int r = row % kR;

    const int v = (lane < kL) ? routes[row * kL + lane] : -1;
    const bool valid = (v > -1);
    bool dup = false;
#pragma unroll
    for (int k = 0; k < kL; ++k) {
        const int vk = __shfl(v, k, 64);
        if (k < lane && vk == v) dup = true;
    }
    const int len  = __popcll(__ballot(valid));
    const int dist = __popcll(__ballot(valid && !dup));

    if (lane == 0) {
        int delta = (kMinLen - len > 0) ? (kMinLen - len) : 0;
        if (len == 0) delta = 0;
        delta += (len - kMaxLen > 0) ? (len - kMaxLen) : 0;
        float add = (float)delta;
        if (r == 0) {
            const float nun = (float)nleft[b] - (hascur[b] ? 1.0f : 0.0f);
            add += nun * (float)kMinLen;
        }
        atomicAdd(&out[OFF_OOB + b], add);
        out[OFF_NSV + row] = (float)dist;
    }
}

extern "C" void kernel_launch(void* const* d_in, const int* in_sizes, int n_in,
                              void* d_out, int out_size, void* d_ws, size_t ws_size,
                              hipStream_t stream) {
    const float* demand  = (const float*)d_in[0];
    const float* transit = (const float*)d_in[1];
    const float* trt     = (const float*)d_in[2];
    const int*   routes  = (const int*)d_in[3];
    const int*   ntrans  = (const int*)d_in[4];
    const int*   haspath = (const int*)d_in[5];
    const int*   nleft   = (const int*)d_in[6];
    const int*   hascur  = (const int*)d_in[7];
    // d_in[8] (n_disconnected_demand_edges) is unused by the reference.
    float* out = (float*)d_out;

    // zero accumulation slots (graph-capturable async ops, ordered on stream)
    (void)hipMemsetAsync(out, 0, OFF_TT * sizeof(float), stream);
    (void)hipMemsetAsync(out + OFF_OOB, 0, kB * sizeof(float), stream);
    // total_route_time passthrough
    (void)hipMemcpyAsync(out + OFF_TRT, trt, kB * sizeof(float),
                         hipMemcpyDeviceToDevice, stream);

    fused_main<<<dim3(kGX, kB), kBlk, 0, stream>>>(demand, transit, ntrans, haspath, out);

    const int nrows = kB * kR;                 // 2560 waves, one per route row
    const int nthreads = nrows * 64;
    routes_kernel<<<(nthreads + 255) / 256, 256, 0, stream>>>(routes, nleft, hascur, out);
}